// Round 1
// baseline (3607.262 us; speedup 1.0000x reference)
//
#include <hip/hip_runtime.h>
#include <hip/hip_bf16.h>
#include <math.h>

// Problem constants (reference: B,T,D = 8,2048,1024; HID=1024, OUT=512, H=4, WIN=9)
#define B_    8
#define T_    2048
#define D_    1024
#define HID_  1024
#define H_    4
#define DK_   256     // HID_/H_
#define NOUT1 512     // D_/2
#define NOUT2 512     // OUT

__device__ __forceinline__ float gelu_f(float x) {
    // exact (erf) GELU
    return 0.5f * x * (1.0f + erff(x * 0.70710678118654752440f));
}

// ---------------------------------------------------------------------------
// Generic tiled f32 GEMM: C[M,N] = epilogue(A[M,K] @ W[K,N] + bias)
//  ALAY: 0 = A row-major [M,K];  1 = A is [B, K, T] "channel" layout (h1),
//        element (m=b*T+t, k) at A[b*K*T + k*T + t]
//  WLAY: 0 = W row-major [K,N];  1 = W stored [N,K] row-major (transposed use)
//  EPI:  0 = +bias           -> C row-major [M,N]
//        1 = +bias +res[m,n] -> C row-major [M,N]
//        2 = gelu(+bias)     -> C in [B, N, T] layout (transposed store)
// Tiles: BM=BN=64, BK=16, 256 threads, 4x4 per thread. All dims divide evenly.
// ---------------------------------------------------------------------------
template<int ALAY, int WLAY, int EPI>
__global__ __launch_bounds__(256) void gemm_k(
    const float* __restrict__ A, const float* __restrict__ W,
    const float* __restrict__ bias, const float* __restrict__ res,
    float* __restrict__ C, int M, int N, int K)
{
    __shared__ float As[16][65];
    __shared__ float Ws[16][65];
    const int tid = threadIdx.x;
    const int tx = tid & 15, ty = tid >> 4;
    const int m0 = blockIdx.x * 64;
    const int n0 = blockIdx.y * 64;
    float acc[4][4] = {};

    for (int k0 = 0; k0 < K; k0 += 16) {
        if (ALAY == 0) {
            for (int i = tid; i < 1024; i += 256) {
                int m = i >> 4, kk = i & 15;
                As[kk][m] = A[(size_t)(m0 + m) * K + (k0 + kk)];
            }
        } else {
            for (int i = tid; i < 1024; i += 256) {
                int kk = i >> 6, mm = i & 63;
                int m = m0 + mm;
                int b = m >> 11, t = m & (T_ - 1);   // T_ == 2048
                As[kk][mm] = A[(size_t)b * K * T_ + (size_t)(k0 + kk) * T_ + t];
            }
        }
        if (WLAY == 0) {
            for (int i = tid; i < 1024; i += 256) {
                int kk = i >> 6, n = i & 63;
                Ws[kk][n] = W[(size_t)(k0 + kk) * N + (n0 + n)];
            }
        } else {
            for (int i = tid; i < 1024; i += 256) {
                int n = i >> 4, kk = i & 15;
                Ws[kk][n] = W[(size_t)(n0 + n) * K + (k0 + kk)];
            }
        }
        __syncthreads();
        #pragma unroll
        for (int kk = 0; kk < 16; ++kk) {
            float a[4], w[4];
            #pragma unroll
            for (int i = 0; i < 4; ++i) a[i] = As[kk][ty * 4 + i];
            #pragma unroll
            for (int j = 0; j < 4; ++j) w[j] = Ws[kk][tx * 4 + j];
            #pragma unroll
            for (int i = 0; i < 4; ++i)
                #pragma unroll
                for (int j = 0; j < 4; ++j)
                    acc[i][j] = fmaf(a[i], w[j], acc[i][j]);
        }
        __syncthreads();
    }

    #pragma unroll
    for (int i = 0; i < 4; ++i) {
        int m = m0 + ty * 4 + i;
        #pragma unroll
        for (int j = 0; j < 4; ++j) {
            int n = n0 + tx * 4 + j;
            float v = acc[i][j] + bias[n];
            if (EPI == 1) v += res[(size_t)m * N + n];
            if (EPI == 2) {
                v = gelu_f(v);
                int b = m >> 11, t = m & (T_ - 1);
                C[(size_t)b * N * T_ + (size_t)n * T_ + t] = v;
            } else {
                C[(size_t)m * N + n] = v;
            }
        }
    }
}

// ---------------------------------------------------------------------------
// Windowed attention: one wave per (b, h, t). Window = [max(0,t-4), min(T-1,t+4)]
// (the clipped WIN=9 mask). scores = q.k/16 + exp(-|aw*dist^2 - ab|), softmax
// over the window, o = sum attn*v. dk=256 -> each lane owns 4 contiguous dims.
// O may alias Q (each wave reads only its own q row before writing o there).
// ---------------------------------------------------------------------------
__global__ __launch_bounds__(256) void attn_k(
    const float* Q, const float* __restrict__ Kp, const float* __restrict__ V,
    float* O, const float* __restrict__ aw_p, const float* __restrict__ ab_p)
{
    int wid  = (blockIdx.x << 2) | (threadIdx.x >> 6);
    int lane = threadIdx.x & 63;
    int t  = wid & (T_ - 1);
    int bh = wid >> 11;          // / T_
    int b  = bh >> 2, h = bh & (H_ - 1);

    size_t rowbase = ((size_t)b * T_ + t) * HID_ + h * DK_;
    float4 q4 = *(const float4*)(Q + rowbase + lane * 4);

    int jlo = max(0, t - 4), jhi = min(T_ - 1, t + 4);
    int cnt = jhi - jlo + 1;
    float aw = *aw_p, ab = *ab_p;

    float sc[9];
    for (int jj = 0; jj < cnt; ++jj) {
        int j = jlo + jj;
        size_t kb = ((size_t)b * T_ + j) * HID_ + h * DK_;
        float4 k4 = *(const float4*)(Kp + kb + lane * 4);
        float p = q4.x * k4.x + q4.y * k4.y + q4.z * k4.z + q4.w * k4.w;
        #pragma unroll
        for (int off = 32; off; off >>= 1) p += __shfl_xor(p, off);
        float dist = fabsf((float)(t - j));
        sc[jj] = p * (1.0f / 16.0f) + expf(-fabsf(aw * dist * dist - ab));
    }
    float mx = -1e30f;
    for (int jj = 0; jj < cnt; ++jj) mx = fmaxf(mx, sc[jj]);
    float sum = 0.0f;
    for (int jj = 0; jj < cnt; ++jj) { sc[jj] = expf(sc[jj] - mx); sum += sc[jj]; }
    float inv = 1.0f / sum;

    float4 o4 = {0.f, 0.f, 0.f, 0.f};
    for (int jj = 0; jj < cnt; ++jj) {
        int j = jlo + jj;
        size_t vb = ((size_t)b * T_ + j) * HID_ + h * DK_;
        float4 v4 = *(const float4*)(V + vb + lane * 4);
        float w = sc[jj] * inv;
        o4.x += w * v4.x; o4.y += w * v4.y; o4.z += w * v4.z; o4.w += w * v4.w;
    }
    *(float4*)(O + rowbase + lane * 4) = o4;
}

// ---------------------------------------------------------------------------
// In-place LayerNorm over D=1024, one 256-thread block per row.
// ---------------------------------------------------------------------------
__device__ __forceinline__ float block_sum(float v, float* sm) {
    #pragma unroll
    for (int off = 32; off; off >>= 1) v += __shfl_xor(v, off);
    int w = threadIdx.x >> 6;
    if ((threadIdx.x & 63) == 0) sm[w] = v;
    __syncthreads();
    float r = sm[0] + sm[1] + sm[2] + sm[3];
    __syncthreads();
    return r;
}

__global__ __launch_bounds__(256) void ln_k(
    float* __restrict__ Y, const float* __restrict__ g, const float* __restrict__ bta)
{
    __shared__ float sm[4];
    float* y = Y + (size_t)blockIdx.x * D_;
    float v[4];
    float s = 0.f;
    #pragma unroll
    for (int i = 0; i < 4; ++i) { v[i] = y[threadIdx.x * 4 + i]; s += v[i]; }
    float mean = block_sum(s, sm) * (1.0f / D_);
    float s2 = 0.f;
    #pragma unroll
    for (int i = 0; i < 4; ++i) { float d = v[i] - mean; s2 += d * d; }
    float var = block_sum(s2, sm) * (1.0f / D_);
    float rstd = rsqrtf(var + 1e-5f);
    #pragma unroll
    for (int i = 0; i < 4; ++i) {
        int idx = threadIdx.x * 4 + i;
        y[idx] = (v[i] - mean) * rstd * g[idx] + bta[idx];
    }
}

// ---------------------------------------------------------------------------
extern "C" void kernel_launch(void* const* d_in, const int* in_sizes, int n_in,
                              void* d_out, int out_size, void* d_ws, size_t ws_size,
                              hipStream_t stream) {
    const float* x    = (const float*)d_in[0];
    // d_in[1] = seq_len (unused by reference)
    const float* Wq   = (const float*)d_in[2];
    const float* bq   = (const float*)d_in[3];
    const float* Wk   = (const float*)d_in[4];
    const float* bk   = (const float*)d_in[5];
    const float* Wv   = (const float*)d_in[6];
    const float* bv   = (const float*)d_in[7];
    const float* Wo   = (const float*)d_in[8];
    const float* bo   = (const float*)d_in[9];
    const float* ln_g = (const float*)d_in[10];
    const float* ln_b = (const float*)d_in[11];
    const float* W1   = (const float*)d_in[12];  // [512, 1024] (row-major [N,K])
    const float* b1   = (const float*)d_in[13];
    const float* W2   = (const float*)d_in[14];  // [512, 512]
    const float* b2   = (const float*)d_in[15];
    const float* adj_w = (const float*)d_in[16];
    const float* adj_b = (const float*)d_in[17];

    const int M = B_ * T_;                  // 16384
    const size_t S = (size_t)M * HID_;      // 16.78M floats

    float* Q  = (float*)d_ws;               // also attention output O (safe alias)
    float* Kb = Q + S;                      // also pre-LN/post-LN Y (safe: K dead after attn)
    float* V  = Kb + S;

    float* xe = (float*)d_out;                       // [B, 512, T]
    float* h1 = xe + (size_t)B_ * NOUT1 * T_;        // [B, 512, T]

    dim3 blk(256);
    dim3 gP(M / 64, HID_ / 64);    // 256 x 16
    dim3 gF(M / 64, NOUT1 / 64);   // 256 x 8

    // QKV projections
    gemm_k<0, 0, 0><<<gP, blk, 0, stream>>>(x, Wq, bq, nullptr, Q,  M, HID_, D_);
    gemm_k<0, 0, 0><<<gP, blk, 0, stream>>>(x, Wk, bk, nullptr, Kb, M, HID_, D_);
    gemm_k<0, 0, 0><<<gP, blk, 0, stream>>>(x, Wv, bv, nullptr, V,  M, HID_, D_);

    // Windowed attention (O overwrites Q in place)
    attn_k<<<dim3((B_ * H_ * T_) / 4), blk, 0, stream>>>(Q, Kb, V, Q, adj_w, adj_b);

    // Output projection + bias + residual -> Y (reuses K buffer)
    gemm_k<0, 0, 1><<<gP, blk, 0, stream>>>(Q, Wo, bo, x, Kb, M, D_, HID_);

    // LayerNorm in place
    ln_k<<<dim3(M), blk, 0, stream>>>(Kb, ln_g, ln_b);

    // FFN1: h1[b,o,t] = gelu(W1 @ y^T + b1); W1 stored [N=512, K=1024]
    gemm_k<0, 1, 2><<<gF, blk, 0, stream>>>(Kb, W1, b1, nullptr, h1, M, NOUT1, D_);

    // FFN2: xe[b,o,t] = gelu(W2 @ h1 + b2); A is [B,K,T] layout, W2 stored [N,K]
    gemm_k<1, 1, 2><<<gF, blk, 0, stream>>>(h1, W2, b2, nullptr, xe, M, NOUT2, NOUT1);
}

// Round 2
// 448.851 us; speedup vs baseline: 8.0366x; 8.0366x over previous
//
#include <hip/hip_runtime.h>
#include <hip/hip_bf16.h>
#include <math.h>

// Problem constants: B,T,D = 8,2048,1024; HID=1024, OUT=512, H=4, WIN=9
#define B_    8
#define T_    2048
#define D_    1024
#define HID_  1024
#define H_    4
#define DK_   256     // HID_/H_

typedef __bf16 bf16x8  __attribute__((ext_vector_type(8)));
typedef __bf16 bf16x4v __attribute__((ext_vector_type(4)));
typedef float  f32x4   __attribute__((ext_vector_type(4)));

__device__ __forceinline__ float gelu_f(float x) {
    return 0.5f * x * (1.0f + erff(x * 0.70710678118654752440f));
}

__device__ __forceinline__ void gload_lds16(const void* g, void* s) {
    __builtin_amdgcn_global_load_lds(
        (const __attribute__((address_space(1))) void*)g,
        (__attribute__((address_space(3))) void*)s, 16, 0, 0);
}

// ---------------------------------------------------------------------------
// bf16 MFMA GEMM, m97 structure: 128x128 tile, BK=32, 4 waves (2x2), 16x16x32
// MFMA, global_load_lds(16B) staging into linear LDS, 2 barriers per K-step.
// A: [M,K] bf16 row-major.  Bt: [N,K] bf16 row-major (i.e. B transposed).
// EPI 0: Cb[m,n]   = bf16(acc + bias[n])                        (QKV)
// EPI 1: Cf[m,n]   = acc + bias[n] + res[m,n]        (f32)      (O-proj + resid)
// EPI 2: Cf[b,n,t] = gelu(acc+bias)  AND  Cb[m,n] = bf16(gelu)  (FFN1)
// EPI 3: Cf[b,n,t] = gelu(acc+bias)                             (FFN2)
// M%128==0, N%128==0, K%32==0 (true for all uses here).
// ---------------------------------------------------------------------------
template<int EPI>
__global__ __launch_bounds__(256) void mm_k(
    const __bf16* __restrict__ A, const __bf16* __restrict__ Bt,
    const float* __restrict__ bias, const float* __restrict__ res,
    float* __restrict__ Cf, __bf16* __restrict__ Cb,
    int M, int N, int K)
{
    __shared__ __bf16 As[128 * 32];   // [row 0..127][k 0..31]
    __shared__ __bf16 Bs[128 * 32];   // [n   0..127][k 0..31]
    const int tid = threadIdx.x;
    const int w   = tid >> 6;         // wave 0..3
    const int l   = tid & 63;
    const int wm  = w >> 1, wn = w & 1;
    const int m0  = blockIdx.x * 128, n0 = blockIdx.y * 128;
    const int lr  = l & 15;           // fragment row/col within 16
    const int lq  = l >> 4;           // k-group (loads) / row-quad (epilogue)

    f32x4 acc[4][4] = {};

    // 512 chunks of 16B per tile; thread stages chunk tid and tid+256.
    // chunk c -> LDS byte c*16; row = c>>2, k-subchunk = (c&3)*8 elements.
    const int ar0 = tid >> 2,          ak0 = (tid & 3) * 8;
    const int ar1 = (tid + 256) >> 2,  ak1 = (tid & 3) * 8;   // (c1&3)==(c0&3)
    char* As_b = (char*)As;
    char* Bs_b = (char*)Bs;
    char* ldsA0 = As_b + (w * 64) * 16;          // wave-uniform bases
    char* ldsA1 = As_b + (w * 64 + 256) * 16;
    char* ldsB0 = Bs_b + (w * 64) * 16;
    char* ldsB1 = Bs_b + (w * 64 + 256) * 16;

    for (int k0 = 0; k0 < K; k0 += 32) {
        gload_lds16(A  + (size_t)(m0 + ar0) * K + k0 + ak0, ldsA0);
        gload_lds16(A  + (size_t)(m0 + ar1) * K + k0 + ak1, ldsA1);
        gload_lds16(Bt + (size_t)(n0 + ar0) * K + k0 + ak0, ldsB0);
        gload_lds16(Bt + (size_t)(n0 + ar1) * K + k0 + ak1, ldsB1);
        __syncthreads();   // vmcnt(0) drain + barrier: tile visible

        const __bf16* Ab = As + (wm * 64 + lr) * 32 + lq * 8;
        const __bf16* Bb = Bs + (wn * 64 + lr) * 32 + lq * 8;
        bf16x8 a[4], b[4];
        #pragma unroll
        for (int i = 0; i < 4; ++i) a[i] = *(const bf16x8*)(Ab + i * 16 * 32);
        #pragma unroll
        for (int j = 0; j < 4; ++j) b[j] = *(const bf16x8*)(Bb + j * 16 * 32);
        #pragma unroll
        for (int i = 0; i < 4; ++i)
            #pragma unroll
            for (int j = 0; j < 4; ++j)
                acc[i][j] = __builtin_amdgcn_mfma_f32_16x16x32_bf16(
                    a[i], b[j], acc[i][j], 0, 0, 0);
        __syncthreads();   // all reads done before next stage
    }

    // C/D layout (m89-verified): col = lane&15, row = (lane>>4)*4 + reg
    #pragma unroll
    for (int i = 0; i < 4; ++i) {
        const int row0 = m0 + wm * 64 + i * 16 + lq * 4;
        #pragma unroll
        for (int j = 0; j < 4; ++j) {
            const int col = n0 + wn * 64 + j * 16 + lr;
            const float bz = bias[col];
            if (EPI == 0) {
                #pragma unroll
                for (int r = 0; r < 4; ++r)
                    Cb[(size_t)(row0 + r) * N + col] = (__bf16)(acc[i][j][r] + bz);
            } else if (EPI == 1) {
                #pragma unroll
                for (int r = 0; r < 4; ++r) {
                    size_t idx = (size_t)(row0 + r) * N + col;
                    Cf[idx] = acc[i][j][r] + bz + res[idx];
                }
            } else {
                float gv[4];
                #pragma unroll
                for (int r = 0; r < 4; ++r) gv[r] = gelu_f(acc[i][j][r] + bz);
                const int bidx = row0 >> 11, t0 = row0 & (T_ - 1);
                float4 g4; g4.x = gv[0]; g4.y = gv[1]; g4.z = gv[2]; g4.w = gv[3];
                *(float4*)(Cf + (size_t)bidx * N * T_ + (size_t)col * T_ + t0) = g4;
                if (EPI == 2) {
                    #pragma unroll
                    for (int r = 0; r < 4; ++r)
                        Cb[(size_t)(row0 + r) * N + col] = (__bf16)gv[r];
                }
            }
        }
    }
}

// ---------------------------------------------------------------------------
// Windowed attention (WIN=9 clipped): one wave per (b,h,t); bf16 in/out.
// O may alias Q (each wave reads only its own q row).
// ---------------------------------------------------------------------------
__global__ __launch_bounds__(256) void attn_k(
    const __bf16* Q, const __bf16* __restrict__ Kp, const __bf16* __restrict__ V,
    __bf16* O, const float* __restrict__ aw_p, const float* __restrict__ ab_p)
{
    int wid  = (blockIdx.x << 2) | (threadIdx.x >> 6);
    int lane = threadIdx.x & 63;
    int t  = wid & (T_ - 1);
    int bh = wid >> 11;
    int b  = bh >> 2, h = bh & (H_ - 1);

    size_t rowbase = ((size_t)b * T_ + t) * HID_ + h * DK_ + lane * 4;
    bf16x4v q4 = *(const bf16x4v*)(Q + rowbase);
    float qx = q4[0], qy = q4[1], qz = q4[2], qw = q4[3];

    int jlo = max(0, t - 4), jhi = min(T_ - 1, t + 4);
    int cnt = jhi - jlo + 1;
    float aw = *aw_p, ab = *ab_p;

    float sc[9];
    for (int jj = 0; jj < cnt; ++jj) {
        int j = jlo + jj;
        bf16x4v k4 = *(const bf16x4v*)(Kp + ((size_t)b * T_ + j) * HID_ + h * DK_ + lane * 4);
        float p = qx * (float)k4[0] + qy * (float)k4[1] + qz * (float)k4[2] + qw * (float)k4[3];
        #pragma unroll
        for (int off = 32; off; off >>= 1) p += __shfl_xor(p, off);
        float dist = fabsf((float)(t - j));
        sc[jj] = p * (1.0f / 16.0f) + expf(-fabsf(aw * dist * dist - ab));
    }
    float mx = -1e30f;
    for (int jj = 0; jj < cnt; ++jj) mx = fmaxf(mx, sc[jj]);
    float sum = 0.0f;
    for (int jj = 0; jj < cnt; ++jj) { sc[jj] = expf(sc[jj] - mx); sum += sc[jj]; }
    float inv = 1.0f / sum;

    float ox = 0.f, oy = 0.f, oz = 0.f, ow = 0.f;
    for (int jj = 0; jj < cnt; ++jj) {
        int j = jlo + jj;
        bf16x4v v4 = *(const bf16x4v*)(V + ((size_t)b * T_ + j) * HID_ + h * DK_ + lane * 4);
        float wgt = sc[jj] * inv;
        ox += wgt * (float)v4[0]; oy += wgt * (float)v4[1];
        oz += wgt * (float)v4[2]; ow += wgt * (float)v4[3];
    }
    bf16x4v o4; o4[0] = (__bf16)ox; o4[1] = (__bf16)oy; o4[2] = (__bf16)oz; o4[3] = (__bf16)ow;
    *(bf16x4v*)(O + rowbase) = o4;
}

// ---------------------------------------------------------------------------
// LayerNorm over D=1024: f32 in -> bf16 out. One 256-thread block per row.
// ---------------------------------------------------------------------------
__device__ __forceinline__ float block_sum(float v, float* sm) {
    #pragma unroll
    for (int off = 32; off; off >>= 1) v += __shfl_xor(v, off);
    if ((threadIdx.x & 63) == 0) sm[threadIdx.x >> 6] = v;
    __syncthreads();
    float r = sm[0] + sm[1] + sm[2] + sm[3];
    __syncthreads();
    return r;
}

__global__ __launch_bounds__(256) void ln_k(
    const float* __restrict__ Y, __bf16* __restrict__ Yb,
    const float* __restrict__ g, const float* __restrict__ bta)
{
    __shared__ float sm[4];
    const float* y = Y + (size_t)blockIdx.x * D_;
    float v[4], s = 0.f;
    float4 v4 = *(const float4*)(y + threadIdx.x * 4);
    v[0] = v4.x; v[1] = v4.y; v[2] = v4.z; v[3] = v4.w;
    s = v[0] + v[1] + v[2] + v[3];
    float mean = block_sum(s, sm) * (1.0f / D_);
    float s2 = 0.f;
    #pragma unroll
    for (int i = 0; i < 4; ++i) { float d = v[i] - mean; s2 += d * d; }
    float rstd = rsqrtf(block_sum(s2, sm) * (1.0f / D_) + 1e-5f);
    bf16x4v o;
    #pragma unroll
    for (int i = 0; i < 4; ++i) {
        int idx = threadIdx.x * 4 + i;
        o[i] = (__bf16)((v[i] - mean) * rstd * g[idx] + bta[idx]);
    }
    *(bf16x4v*)(Yb + (size_t)blockIdx.x * D_ + threadIdx.x * 4) = o;
}

// ---------------------------------------------------------------------------
// Casts: f32 -> bf16 (vectorized), and f32 [K,N] -> bf16 [N,K] tiled transpose.
// ---------------------------------------------------------------------------
__global__ __launch_bounds__(256) void cast_k(
    const float4* __restrict__ in, bf16x4v* __restrict__ out, int n4)
{
    int i = blockIdx.x * 256 + threadIdx.x;
    if (i < n4) {
        float4 v = in[i];
        bf16x4v o; o[0] = (__bf16)v.x; o[1] = (__bf16)v.y; o[2] = (__bf16)v.z; o[3] = (__bf16)v.w;
        out[i] = o;
    }
}

__global__ void castT_k(const float* __restrict__ in, __bf16* __restrict__ out,
                        int K, int N)   // out[n*K+k] = in[k*N+n]
{
    __shared__ float tbuf[32][33];
    int k0 = blockIdx.x * 32, n0 = blockIdx.y * 32;
    for (int r = threadIdx.y; r < 32; r += 8)
        tbuf[r][threadIdx.x] = in[(size_t)(k0 + r) * N + n0 + threadIdx.x];
    __syncthreads();
    for (int r = threadIdx.y; r < 32; r += 8)
        out[(size_t)(n0 + r) * K + k0 + threadIdx.x] = (__bf16)tbuf[threadIdx.x][r];
}

// ---------------------------------------------------------------------------
extern "C" void kernel_launch(void* const* d_in, const int* in_sizes, int n_in,
                              void* d_out, int out_size, void* d_ws, size_t ws_size,
                              hipStream_t stream) {
    const float* x    = (const float*)d_in[0];
    const float* Wq   = (const float*)d_in[2];
    const float* bq   = (const float*)d_in[3];
    const float* Wk   = (const float*)d_in[4];
    const float* bk   = (const float*)d_in[5];
    const float* Wv   = (const float*)d_in[6];
    const float* bv   = (const float*)d_in[7];
    const float* Wo   = (const float*)d_in[8];
    const float* bo   = (const float*)d_in[9];
    const float* ln_g = (const float*)d_in[10];
    const float* ln_b = (const float*)d_in[11];
    const float* W1   = (const float*)d_in[12];  // [512,1024] already [N,K]
    const float* b1   = (const float*)d_in[13];
    const float* W2   = (const float*)d_in[14];  // [512,512]  already [N,K]
    const float* b2   = (const float*)d_in[15];
    const float* adj_w = (const float*)d_in[16];
    const float* adj_b = (const float*)d_in[17];

    const int M = B_ * T_;                  // 16384
    const size_t S = (size_t)M * HID_;      // 16.78M elems

    // Workspace layout (bf16 elems unless noted); total ~185.5 MiB.
    __bf16* Qb  = (__bf16*)d_ws;            // S  (also attention output O)
    __bf16* Kb  = Qb + S;                   // S  \ dead after attn:
    __bf16* Vb  = Kb + S;                   // S  / Y(f32, S) aliases Kb..Vb end
    float*  Y   = (float*)Kb;               // S floats = spans Kb+Vb exactly
    __bf16* xb  = Vb + S;                   // S
    __bf16* Wqt = xb + S;                   // 1M
    __bf16* Wkt = Wqt + 1024 * 1024;
    __bf16* Wvt = Wkt + 1024 * 1024;
    __bf16* Wot = Wvt + 1024 * 1024;
    __bf16* W1b = Wot + 1024 * 1024;        // 512*1024
    __bf16* W2b = W1b + 512 * 1024;         // 512*512
    __bf16* Yb  = W2b + 512 * 512;          // S
    __bf16* h1b = Yb + S;                   // M*512

    float* xe = (float*)d_out;                         // [B,512,T]
    float* h1 = xe + (size_t)B_ * 512 * T_;            // [B,512,T]

    dim3 blk(256);

    // --- precision conversion ---
    cast_k<<<dim3((int)(S / 4 / 256)), blk, 0, stream>>>((const float4*)x, (bf16x4v*)xb, (int)(S / 4));
    dim3 tgrid(D_ / 32, HID_ / 32);
    castT_k<<<tgrid, dim3(32, 8), 0, stream>>>(Wq, Wqt, D_, HID_);
    castT_k<<<tgrid, dim3(32, 8), 0, stream>>>(Wk, Wkt, D_, HID_);
    castT_k<<<tgrid, dim3(32, 8), 0, stream>>>(Wv, Wvt, D_, HID_);
    castT_k<<<tgrid, dim3(32, 8), 0, stream>>>(Wo, Wot, HID_, D_);
    cast_k<<<dim3(512), blk, 0, stream>>>((const float4*)W1, (bf16x4v*)W1b, 512 * 1024 / 4);
    cast_k<<<dim3(256), blk, 0, stream>>>((const float4*)W2, (bf16x4v*)W2b, 512 * 512 / 4);

    // --- QKV projections (bf16 MFMA) ---
    dim3 gP(M / 128, HID_ / 128);   // 128 x 8
    mm_k<0><<<gP, blk, 0, stream>>>(xb, Wqt, bq, nullptr, nullptr, Qb, M, HID_, D_);
    mm_k<0><<<gP, blk, 0, stream>>>(xb, Wkt, bk, nullptr, nullptr, Kb, M, HID_, D_);
    mm_k<0><<<gP, blk, 0, stream>>>(xb, Wvt, bv, nullptr, nullptr, Vb, M, HID_, D_);

    // --- windowed attention (O overwrites Qb) ---
    attn_k<<<dim3((B_ * H_ * T_) / 4), blk, 0, stream>>>(Qb, Kb, Vb, Qb, adj_w, adj_b);

    // --- O-projection + bias + residual -> Y f32 (over K/V region) ---
    mm_k<1><<<gP, blk, 0, stream>>>(Qb, Wot, bo, x, Y, nullptr, M, D_, HID_);

    // --- LayerNorm -> bf16 ---
    ln_k<<<dim3(M), blk, 0, stream>>>(Y, Yb, ln_g, ln_b);

    // --- FFN1: gelu(W1 @ y^T): f32 transposed to h1, bf16 row-major to h1b ---
    dim3 gF(M / 128, 512 / 128);    // 128 x 4
    mm_k<2><<<gF, blk, 0, stream>>>(Yb, W1b, b1, nullptr, h1, h1b, M, 512, D_);

    // --- FFN2: gelu(W2 @ h1): f32 transposed to xe ---
    mm_k<3><<<gF, blk, 0, stream>>>(h1b, W2b, b2, nullptr, xe, nullptr, M, 512, 512);
}

// Round 3
// 389.715 us; speedup vs baseline: 9.2562x; 1.1517x over previous
//
#include <hip/hip_runtime.h>
#include <hip/hip_bf16.h>
#include <math.h>

// Problem constants: B,T,D = 8,2048,1024; HID=1024, OUT=512, H=4, WIN=9
#define B_    8
#define T_    2048
#define D_    1024
#define HID_  1024
#define H_    4
#define DK_   256     // HID_/H_
#define S_ELEMS ((size_t)16384 * 1024)   // M * HID

typedef __bf16 bf16x8  __attribute__((ext_vector_type(8)));
typedef __bf16 bf16x4v __attribute__((ext_vector_type(4)));
typedef float  f32x4   __attribute__((ext_vector_type(4)));

__device__ __forceinline__ float gelu_f(float x) {
    return 0.5f * x * (1.0f + erff(x * 0.70710678118654752440f));
}

__device__ __forceinline__ void gload_lds16(const void* g, void* s) {
    __builtin_amdgcn_global_load_lds(
        (const __attribute__((address_space(1))) void*)g,
        (__attribute__((address_space(3))) void*)s, 16, 0, 0);
}

// ---------------------------------------------------------------------------
// 256x256 deep-pipelined bf16 GEMM. BK=64, 8 waves (2Mx4N), 512 threads.
// LDS 128 KiB: 2 bufs x (A[256x64] + B[256x64]) bf16, XOR-swizzled reads
// (row*128 + ((chunk ^ (row&7))<<4)) staged via inverse-swizzled global src +
// linear global_load_lds dest (both-sides involution, rule 21).
// Pipeline: issue next tile A(4 loads) -> vmcnt(4) -> s_barrier ->
//   phase ks=0 {12 ds_read_b128, stage next B(4), barrier, setprio, 32 MFMA} ->
//   phase ks=1 {12 ds_read_b128, barrier, setprio, 32 MFMA} -> barrier.
// vmcnt never drains to 0 in the main loop (T3/T4); counted waits derived from
// FIFO retirement: outstanding [tA4,tB4,(t+1)A4]=12 -> vmcnt(4) completes tile t.
// A: [M,K] bf16 row-major.  Bt: [N,K] bf16 row-major.
// EPI 0: QKV fused - Cb+sel*S_ELEMS gets bf16(acc+bias[col]); sel = col>>10
// EPI 1: Cf[m,n] = acc + bias[n] + res[m,n]  (f32)
// Requires M%256==0, N%256==0, K%64==0, K>=128.
// ---------------------------------------------------------------------------
template<int EPI>
__global__ __launch_bounds__(512) void gemm256_k(
    const __bf16* __restrict__ A, const __bf16* __restrict__ Bt,
    const float* __restrict__ bias, const float* __restrict__ res,
    float* __restrict__ Cf, __bf16* __restrict__ Cb,
    int M, int N, int K)
{
    __shared__ __bf16 lds[2][2][256 * 64];   // [buf][A/B][row*64 + k] (swizzled)
    const int tid = threadIdx.x;
    const int w  = tid >> 6, l = tid & 63;
    const int wm = w >> 2,  wn = w & 3;       // 2 x 4 wave grid
    const int lr = l & 15, lq = l >> 4, lx = l & 7;
    const int m0 = blockIdx.x * 256, n0 = blockIdx.y * 256;
    const int nt = K >> 6;

    f32x4 acc[8][4] = {};

    // Staging geometry: 2048 16B-chunks per panel; thread owns chunks
    // i = tid + c*512 (c=0..3). Linear LDS dest byte = i*16; global source
    // chunk = (row = i>>3, slot = (i&7) ^ (row&7))  [inverse swizzle].
    int srow[4], sslot[4];
    #pragma unroll
    for (int c = 0; c < 4; ++c) {
        int i = tid + c * 512;
        srow[c]  = i >> 3;
        sslot[c] = (i & 7) ^ (srow[c] & 7);
    }
    const int ldsu = (w * 64) * 16;          // wave-uniform part of dest

    auto stageA = [&](int t) {
        char* dst = (char*)&lds[t & 1][0][0];
        #pragma unroll
        for (int c = 0; c < 4; ++c)
            gload_lds16((const char*)(A + (size_t)(m0 + srow[c]) * K + t * 64) + (sslot[c] << 4),
                        dst + ldsu + c * 512 * 16);
    };
    auto stageB = [&](int t) {
        char* dst = (char*)&lds[t & 1][1][0];
        #pragma unroll
        for (int c = 0; c < 4; ++c)
            gload_lds16((const char*)(Bt + (size_t)(n0 + srow[c]) * K + t * 64) + (sslot[c] << 4),
                        dst + ldsu + c * 512 * 16);
    };

    stageA(0);
    stageB(0);

    for (int t = 0; t < nt; ++t) {
        const int cur = t & 1;
        if (t + 1 < nt) {
            stageA(t + 1);
            asm volatile("s_waitcnt vmcnt(4)" ::: "memory");
        } else {
            asm volatile("s_waitcnt vmcnt(0)" ::: "memory");
        }
        __builtin_amdgcn_s_barrier();        // tile t visible in LDS
        asm volatile("" ::: "memory");

        const char* Ap = (const char*)&lds[cur][0][0];
        const char* Bp = (const char*)&lds[cur][1][0];

        #pragma unroll
        for (int ks = 0; ks < 2; ++ks) {
            bf16x8 af[8], bfr[4];
            #pragma unroll
            for (int fi = 0; fi < 8; ++fi)
                af[fi] = *(const bf16x8*)(Ap + (wm * 128 + fi * 16 + lr) * 128
                                             + ((((ks << 2) | lq) ^ lx) << 4));
            #pragma unroll
            for (int fj = 0; fj < 4; ++fj)
                bfr[fj] = *(const bf16x8*)(Bp + (wn * 64 + fj * 16 + lr) * 128
                                              + ((((ks << 2) | lq) ^ lx) << 4));
            if (ks == 0 && t + 1 < nt) stageB(t + 1);
            __builtin_amdgcn_s_barrier();    // phase alignment
            asm volatile("" ::: "memory");
            __builtin_amdgcn_s_setprio(1);
            #pragma unroll
            for (int fi = 0; fi < 8; ++fi)
                #pragma unroll
                for (int fj = 0; fj < 4; ++fj)
                    acc[fi][fj] = __builtin_amdgcn_mfma_f32_16x16x32_bf16(
                        af[fi], bfr[fj], acc[fi][fj], 0, 0, 0);
            __builtin_amdgcn_s_setprio(0);
            __builtin_amdgcn_s_barrier();    // all reads of buf[cur] done below here
            asm volatile("" ::: "memory");
        }
    }

    // C/D layout: col = lane&15, row = (lane>>4)*4 + reg
    #pragma unroll
    for (int fi = 0; fi < 8; ++fi) {
        const int row0 = m0 + wm * 128 + fi * 16 + lq * 4;
        #pragma unroll
        for (int fj = 0; fj < 4; ++fj) {
            const int col = n0 + wn * 64 + fj * 16 + lr;
            const float bz = bias[col];
            if (EPI == 0) {
                const int sel = col >> 10, cl = col & 1023;
                __bf16* out = Cb + (size_t)sel * S_ELEMS + (size_t)row0 * 1024 + cl;
                #pragma unroll
                for (int r = 0; r < 4; ++r)
                    out[(size_t)r * 1024] = (__bf16)(acc[fi][fj][r] + bz);
            } else {
                #pragma unroll
                for (int r = 0; r < 4; ++r) {
                    size_t idx = (size_t)(row0 + r) * N + col;
                    Cf[idx] = acc[fi][fj][r] + bz + res[idx];
                }
            }
        }
    }
}

// ---------------------------------------------------------------------------
// m97-structure 128x128 bf16 GEMM (kept for FFN1/FFN2, N=512 -> full-GPU grid)
// EPI 2: Cf[b,n,t] = gelu(acc+bias)  AND  Cb[m,n] = bf16(gelu)  (FFN1)
// EPI 3: Cf[b,n,t] = gelu(acc+bias)                             (FFN2)
// ---------------------------------------------------------------------------
template<int EPI>
__global__ __launch_bounds__(256) void mm_k(
    const __bf16* __restrict__ A, const __bf16* __restrict__ Bt,
    const float* __restrict__ bias, const float* __restrict__ res,
    float* __restrict__ Cf, __bf16* __restrict__ Cb,
    int M, int N, int K)
{
    __shared__ __bf16 As[128 * 32];
    __shared__ __bf16 Bs[128 * 32];
    const int tid = threadIdx.x;
    const int w   = tid >> 6;
    const int l   = tid & 63;
    const int wm  = w >> 1, wn = w & 1;
    const int m0  = blockIdx.x * 128, n0 = blockIdx.y * 128;
    const int lr  = l & 15;
    const int lq  = l >> 4;

    f32x4 acc[4][4] = {};

    const int ar0 = tid >> 2,          ak0 = (tid & 3) * 8;
    const int ar1 = (tid + 256) >> 2,  ak1 = (tid & 3) * 8;
    char* As_b = (char*)As;
    char* Bs_b = (char*)Bs;
    char* ldsA0 = As_b + (w * 64) * 16;
    char* ldsA1 = As_b + (w * 64 + 256) * 16;
    char* ldsB0 = Bs_b + (w * 64) * 16;
    char* ldsB1 = Bs_b + (w * 64 + 256) * 16;

    for (int k0 = 0; k0 < K; k0 += 32) {
        gload_lds16(A  + (size_t)(m0 + ar0) * K + k0 + ak0, ldsA0);
        gload_lds16(A  + (size_t)(m0 + ar1) * K + k0 + ak1, ldsA1);
        gload_lds16(Bt + (size_t)(n0 + ar0) * K + k0 + ak0, ldsB0);
        gload_lds16(Bt + (size_t)(n0 + ar1) * K + k0 + ak1, ldsB1);
        __syncthreads();

        const __bf16* Ab = As + (wm * 64 + lr) * 32 + lq * 8;
        const __bf16* Bb = Bs + (wn * 64 + lr) * 32 + lq * 8;
        bf16x8 a[4], b[4];
        #pragma unroll
        for (int i = 0; i < 4; ++i) a[i] = *(const bf16x8*)(Ab + i * 16 * 32);
        #pragma unroll
        for (int j = 0; j < 4; ++j) b[j] = *(const bf16x8*)(Bb + j * 16 * 32);
        #pragma unroll
        for (int i = 0; i < 4; ++i)
            #pragma unroll
            for (int j = 0; j < 4; ++j)
                acc[i][j] = __builtin_amdgcn_mfma_f32_16x16x32_bf16(
                    a[i], b[j], acc[i][j], 0, 0, 0);
        __syncthreads();
    }

    #pragma unroll
    for (int i = 0; i < 4; ++i) {
        const int row0 = m0 + wm * 64 + i * 16 + lq * 4;
        #pragma unroll
        for (int j = 0; j < 4; ++j) {
            const int col = n0 + wn * 64 + j * 16 + lr;
            const float bz = bias[col];
            float gv[4];
            #pragma unroll
            for (int r = 0; r < 4; ++r) gv[r] = gelu_f(acc[i][j][r] + bz);
            const int bidx = row0 >> 11, t0 = row0 & (T_ - 1);
            float4 g4; g4.x = gv[0]; g4.y = gv[1]; g4.z = gv[2]; g4.w = gv[3];
            *(float4*)(Cf + (size_t)bidx * N * T_ + (size_t)col * T_ + t0) = g4;
            if (EPI == 2) {
                #pragma unroll
                for (int r = 0; r < 4; ++r)
                    Cb[(size_t)(row0 + r) * N + col] = (__bf16)gv[r];
            }
        }
    }
}

// ---------------------------------------------------------------------------
// Windowed attention (WIN=9 clipped): one wave per (b,h,t); bf16 in/out.
// ---------------------------------------------------------------------------
__global__ __launch_bounds__(256) void attn_k(
    const __bf16* Q, const __bf16* __restrict__ Kp, const __bf16* __restrict__ V,
    __bf16* O, const float* __restrict__ aw_p, const float* __restrict__ ab_p)
{
    int wid  = (blockIdx.x << 2) | (threadIdx.x >> 6);
    int lane = threadIdx.x & 63;
    int t  = wid & (T_ - 1);
    int bh = wid >> 11;
    int b  = bh >> 2, h = bh & (H_ - 1);

    size_t rowbase = ((size_t)b * T_ + t) * HID_ + h * DK_ + lane * 4;
    bf16x4v q4 = *(const bf16x4v*)(Q + rowbase);
    float qx = q4[0], qy = q4[1], qz = q4[2], qw = q4[3];

    int jlo = max(0, t - 4), jhi = min(T_ - 1, t + 4);
    int cnt = jhi - jlo + 1;
    float aw = *aw_p, ab = *ab_p;

    float sc[9];
    for (int jj = 0; jj < cnt; ++jj) {
        int j = jlo + jj;
        bf16x4v k4 = *(const bf16x4v*)(Kp + ((size_t)b * T_ + j) * HID_ + h * DK_ + lane * 4);
        float p = qx * (float)k4[0] + qy * (float)k4[1] + qz * (float)k4[2] + qw * (float)k4[3];
        #pragma unroll
        for (int off = 32; off; off >>= 1) p += __shfl_xor(p, off);
        float dist = fabsf((float)(t - j));
        sc[jj] = p * (1.0f / 16.0f) + expf(-fabsf(aw * dist * dist - ab));
    }
    float mx = -1e30f;
    for (int jj = 0; jj < cnt; ++jj) mx = fmaxf(mx, sc[jj]);
    float sum = 0.0f;
    for (int jj = 0; jj < cnt; ++jj) { sc[jj] = expf(sc[jj] - mx); sum += sc[jj]; }
    float inv = 1.0f / sum;

    float ox = 0.f, oy = 0.f, oz = 0.f, ow = 0.f;
    for (int jj = 0; jj < cnt; ++jj) {
        int j = jlo + jj;
        bf16x4v v4 = *(const bf16x4v*)(V + ((size_t)b * T_ + j) * HID_ + h * DK_ + lane * 4);
        float wgt = sc[jj] * inv;
        ox += wgt * (float)v4[0]; oy += wgt * (float)v4[1];
        oz += wgt * (float)v4[2]; ow += wgt * (float)v4[3];
    }
    bf16x4v o4; o4[0] = (__bf16)ox; o4[1] = (__bf16)oy; o4[2] = (__bf16)oz; o4[3] = (__bf16)ow;
    *(bf16x4v*)(O + rowbase) = o4;
}

// ---------------------------------------------------------------------------
// LayerNorm over D=1024: f32 in -> bf16 out. One 256-thread block per row.
// ---------------------------------------------------------------------------
__device__ __forceinline__ float block_sum(float v, float* sm) {
    #pragma unroll
    for (int off = 32; off; off >>= 1) v += __shfl_xor(v, off);
    if ((threadIdx.x & 63) == 0) sm[threadIdx.x >> 6] = v;
    __syncthreads();
    float r = sm[0] + sm[1] + sm[2] + sm[3];
    __syncthreads();
    return r;
}

__global__ __launch_bounds__(256) void ln_k(
    const float* __restrict__ Y, __bf16* __restrict__ Yb,
    const float* __restrict__ g, const float* __restrict__ bta)
{
    __shared__ float sm[4];
    const float* y = Y + (size_t)blockIdx.x * D_;
    float v[4];
    float4 v4 = *(const float4*)(y + threadIdx.x * 4);
    v[0] = v4.x; v[1] = v4.y; v[2] = v4.z; v[3] = v4.w;
    float mean = block_sum(v[0] + v[1] + v[2] + v[3], sm) * (1.0f / D_);
    float s2 = 0.f;
    #pragma unroll
    for (int i = 0; i < 4; ++i) { float d = v[i] - mean; s2 += d * d; }
    float rstd = rsqrtf(block_sum(s2, sm) * (1.0f / D_) + 1e-5f);
    bf16x4v o;
    #pragma unroll
    for (int i = 0; i < 4; ++i) {
        int idx = threadIdx.x * 4 + i;
        o[i] = (__bf16)((v[i] - mean) * rstd * g[idx] + bta[idx]);
    }
    *(bf16x4v*)(Yb + (size_t)blockIdx.x * D_ + threadIdx.x * 4) = o;
}

// ---------------------------------------------------------------------------
// Casts and packing
// ---------------------------------------------------------------------------
__global__ __launch_bounds__(256) void cast_k(
    const float4* __restrict__ in, bf16x4v* __restrict__ out, int n4)
{
    int i = blockIdx.x * 256 + threadIdx.x;
    if (i < n4) {
        float4 v = in[i];
        bf16x4v o; o[0] = (__bf16)v.x; o[1] = (__bf16)v.y; o[2] = (__bf16)v.z; o[3] = (__bf16)v.w;
        out[i] = o;
    }
}

__global__ void castT_k(const float* __restrict__ in, __bf16* __restrict__ out,
                        int K, int N)   // out[n*K+k] = in[k*N+n]
{
    __shared__ float tbuf[32][33];
    int k0 = blockIdx.x * 32, n0 = blockIdx.y * 32;
    for (int r = threadIdx.y; r < 32; r += 8)
        tbuf[r][threadIdx.x] = in[(size_t)(k0 + r) * N + n0 + threadIdx.x];
    __syncthreads();
    for (int r = threadIdx.y; r < 32; r += 8)
        out[(size_t)(n0 + r) * K + k0 + threadIdx.x] = (__bf16)tbuf[threadIdx.x][r];
}

__global__ void packb_k(const float* __restrict__ bq, const float* __restrict__ bk,
                        const float* __restrict__ bv, float* __restrict__ out)
{
    int i = blockIdx.x * 256 + threadIdx.x;   // grid 12 x 256 = 3072
    out[i] = (i < 1024) ? bq[i] : ((i < 2048) ? bk[i - 1024] : bv[i - 2048]);
}

// ---------------------------------------------------------------------------
extern "C" void kernel_launch(void* const* d_in, const int* in_sizes, int n_in,
                              void* d_out, int out_size, void* d_ws, size_t ws_size,
                              hipStream_t stream) {
    const float* x    = (const float*)d_in[0];
    const float* Wq   = (const float*)d_in[2];
    const float* bq   = (const float*)d_in[3];
    const float* Wk   = (const float*)d_in[4];
    const float* bk   = (const float*)d_in[5];
    const float* Wv   = (const float*)d_in[6];
    const float* bv   = (const float*)d_in[7];
    const float* Wo   = (const float*)d_in[8];
    const float* bo   = (const float*)d_in[9];
    const float* ln_g = (const float*)d_in[10];
    const float* ln_b = (const float*)d_in[11];
    const float* W1   = (const float*)d_in[12];  // [512,1024] already [N,K]
    const float* b1   = (const float*)d_in[13];
    const float* W2   = (const float*)d_in[14];  // [512,512]  already [N,K]
    const float* b2   = (const float*)d_in[15];
    const float* adj_w = (const float*)d_in[16];
    const float* adj_b = (const float*)d_in[17];

    const int M = B_ * T_;                  // 16384
    const size_t S = S_ELEMS;               // 16.78M elems

    // Workspace layout (bf16 elems unless noted)
    __bf16* Qb   = (__bf16*)d_ws;           // S  (also attention output O)
    __bf16* Kb   = Qb + S;                  // S  \ dead after attn:
    __bf16* Vb   = Kb + S;                  // S  / Y(f32,S) aliases Kb..Vb
    float*  Y    = (float*)Kb;
    __bf16* xb   = Vb + S;                  // S
    __bf16* Wqkv = xb + S;                  // 3*1M  ([3072,1024] bf16, N-major)
    __bf16* Wot  = Wqkv + 3 * 1024 * 1024;  // 1M
    __bf16* W1b  = Wot + 1024 * 1024;       // 512*1024
    __bf16* W2b  = W1b + 512 * 1024;        // 512*512
    __bf16* Yb   = W2b + 512 * 512;         // S
    __bf16* h1b  = Yb + S;                  // M*512
    float*  bqkvd = (float*)(h1b + (size_t)M * 512);  // 3072 f32

    float* xe = (float*)d_out;                         // [B,512,T]
    float* h1 = xe + (size_t)B_ * 512 * T_;            // [B,512,T]

    dim3 blk(256);

    // --- precision conversion / packing ---
    cast_k<<<dim3((int)(S / 4 / 256)), blk, 0, stream>>>((const float4*)x, (bf16x4v*)xb, (int)(S / 4));
    dim3 tgrid(D_ / 32, HID_ / 32);
    castT_k<<<tgrid, dim3(32, 8), 0, stream>>>(Wq, Wqkv,                    D_, HID_);
    castT_k<<<tgrid, dim3(32, 8), 0, stream>>>(Wk, Wqkv + 1024 * 1024,     D_, HID_);
    castT_k<<<tgrid, dim3(32, 8), 0, stream>>>(Wv, Wqkv + 2 * 1024 * 1024, D_, HID_);
    castT_k<<<tgrid, dim3(32, 8), 0, stream>>>(Wo, Wot, HID_, D_);
    cast_k<<<dim3(512), blk, 0, stream>>>((const float4*)W1, (bf16x4v*)W1b, 512 * 1024 / 4);
    cast_k<<<dim3(256), blk, 0, stream>>>((const float4*)W2, (bf16x4v*)W2b, 512 * 512 / 4);
    packb_k<<<dim3(12), blk, 0, stream>>>(bq, bk, bv, bqkvd);

    // --- QKV fused projection (256^2 pipelined MFMA): N=3072 ---
    gemm256_k<0><<<dim3(M / 256, 3072 / 256), dim3(512), 0, stream>>>(
        xb, Wqkv, bqkvd, nullptr, nullptr, Qb, M, 3072, D_);

    // --- windowed attention (O overwrites Qb) ---
    attn_k<<<dim3((B_ * H_ * T_) / 4), blk, 0, stream>>>(Qb, Kb, Vb, Qb, adj_w, adj_b);

    // --- O-projection + bias + residual -> Y f32 ---
    gemm256_k<1><<<dim3(M / 256, HID_ / 256), dim3(512), 0, stream>>>(
        Qb, Wot, bo, x, Y, nullptr, M, D_, HID_);

    // --- LayerNorm -> bf16 ---
    ln_k<<<dim3(M), blk, 0, stream>>>(Y, Yb, ln_g, ln_b);

    // --- FFN1: gelu(W1 @ y^T): f32 transposed to h1, bf16 row-major to h1b ---
    dim3 gF(M / 128, 512 / 128);
    mm_k<2><<<gF, blk, 0, stream>>>(Yb, W1b, b1, nullptr, h1, h1b, M, 512, D_);

    // --- FFN2: gelu(W2 @ h1): f32 transposed to xe ---
    mm_k<3><<<gF, blk, 0, stream>>>(h1b, W2b, b2, nullptr, xe, nullptr, M, 512, 512);
}